// Round 4
// baseline (132.242 us; speedup 1.0000x reference)
//
#include <hip/hip_runtime.h>
#include <hip/hip_cooperative_groups.h>

namespace cg = cooperative_groups;

// Problem constants (match reference)
#define BB 2
#define NN 131072
#define MM 512
#define GG 20
#define VV (GG * GG * GG)      // 8000
#define NBLKX 128              // blocks per batch (grid = NBLKX x BB = 256 = #CUs)

// Workspace layout:
//   0      partialMin : B*NBLKX*3 floats (3072 B) -- written P1, read P2
//   4096   sums       : B*V*10 floats (640000 B)  -- zeroed P0, atomics P3
#define OFF_PARTIAL 0
#define OFF_SUMS    4096
#define SUM_WORDS   (BB * VV * 10)    // 160000

__device__ __forceinline__ int vox_coord(float p, float mn) {
    int i = (int)floorf((p - mn) * 2.0f);   // *2 == /0.5 (exact pow2)
    return min(max(i, 0), GG - 1);
}

__global__ __launch_bounds__(256) void vox_coop(const float* __restrict__ x,
                                                const int* __restrict__ sidx,
                                                char* __restrict__ ws,
                                                float* __restrict__ out) {
    cg::grid_group grid = cg::this_grid();
    const int b = blockIdx.y;
    const int tid = blockIdx.x * 256 + threadIdx.x;           // 0..32767 per batch
    const int gtid = (b * NBLKX + blockIdx.x) * 256 + threadIdx.x;  // 0..65535

    float* partial = (float*)(ws + OFF_PARTIAL);
    float* sums = (float*)(ws + OFF_SUMS);

    // ---- P0: distributed zero of sums (no memset node) ----
    {
        float* z = sums;
        for (int i = gtid; i < SUM_WORDS; i += NBLKX * BB * 256) z[i] = 0.0f;
    }

    // ---- P1: load 4 points (3 x float4) into REGISTERS, block min ----
    const float4* xb = (const float4*)(x + (size_t)b * NN * 3);
    float4 f0 = xb[3 * tid + 0];
    float4 f1 = xb[3 * tid + 1];
    float4 f2 = xb[3 * tid + 2];
    float px0 = f0.x, px1 = f0.w, px2 = f1.z, px3 = f2.y;
    float py0 = f0.y, py1 = f1.x, py2 = f1.w, py3 = f2.z;
    float pz0 = f0.z, pz1 = f1.y, pz2 = f2.x, pz3 = f2.w;

    float mx = fminf(fminf(px0, px1), fminf(px2, px3));
    float my = fminf(fminf(py0, py1), fminf(py2, py3));
    float mz = fminf(fminf(pz0, pz1), fminf(pz2, pz3));
    for (int off = 32; off > 0; off >>= 1) {
        mx = fminf(mx, __shfl_down(mx, off, 64));
        my = fminf(my, __shfl_down(my, off, 64));
        mz = fminf(mz, __shfl_down(mz, off, 64));
    }
    __shared__ float lmin[4][3];
    {
        int wave = threadIdx.x >> 6;
        if ((threadIdx.x & 63) == 0) {
            lmin[wave][0] = mx; lmin[wave][1] = my; lmin[wave][2] = mz;
        }
        __syncthreads();
        if (threadIdx.x == 0) {
            float* pm = partial + (b * NBLKX + blockIdx.x) * 3;
            pm[0] = fminf(fminf(lmin[0][0], lmin[1][0]), fminf(lmin[2][0], lmin[3][0]));
            pm[1] = fminf(fminf(lmin[0][1], lmin[1][1]), fminf(lmin[2][1], lmin[3][1]));
            pm[2] = fminf(fminf(lmin[0][2], lmin[1][2]), fminf(lmin[2][2], lmin[3][2]));
        }
    }

    grid.sync();   // partials visible; sums zero visible

    // ---- P2: every block reduces its batch's 128 partials (L2-hot, no winner) ----
    __shared__ float smin[3];
    {
        float rx = 1e30f, ry = 1e30f, rz = 1e30f;
        if (threadIdx.x < NBLKX) {
            const float* pm = partial + (b * NBLKX + threadIdx.x) * 3;
            rx = pm[0]; ry = pm[1]; rz = pm[2];
        }
        for (int off = 32; off > 0; off >>= 1) {
            rx = fminf(rx, __shfl_down(rx, off, 64));
            ry = fminf(ry, __shfl_down(ry, off, 64));
            rz = fminf(rz, __shfl_down(rz, off, 64));
        }
        __syncthreads();   // reuse lmin
        int wave = threadIdx.x >> 6;
        if ((threadIdx.x & 63) == 0 && wave < 2) {
            lmin[wave][0] = rx; lmin[wave][1] = ry; lmin[wave][2] = rz;
        }
        __syncthreads();
        if (threadIdx.x < 3) {
            smin[threadIdx.x] = fminf(lmin[0][threadIdx.x], lmin[1][threadIdx.x]);
        }
    }

    // ---- P2b: per-block LDS flag table from the 512 sampled points ----
    __shared__ unsigned char flags[VV];
    for (int i = threadIdx.x; i < VV; i += 256) flags[i] = 0;
    __syncthreads();
    const float mnx = smin[0], mny = smin[1], mnz = smin[2];

    int myflat0, myflat1;   // kept for P4 (this block's sample flats)
    {
        // s = threadIdx.x and threadIdx.x + 256 for batch b
        int s0 = threadIdx.x, s1 = threadIdx.x + 256;
        int pi0 = sidx[b * MM + s0];
        int pi1 = sidx[b * MM + s1];
        const float* p0 = x + ((size_t)b * NN + pi0) * 3;
        const float* p1 = x + ((size_t)b * NN + pi1) * 3;
        myflat0 = (vox_coord(p0[0], mnx) * GG + vox_coord(p0[1], mny)) * GG +
                  vox_coord(p0[2], mnz);
        myflat1 = (vox_coord(p1[0], mnx) * GG + vox_coord(p1[1], mny)) * GG +
                  vox_coord(p1[2], mnz);
        flags[myflat0] = 1;
        flags[myflat1] = 1;
    }
    __syncthreads();

    // ---- P3: accumulate registered points into per-voxel sums ----
    {
        float* sb = sums + (size_t)b * VV * 10;
        float PX[4] = {px0, px1, px2, px3};
        float PY[4] = {py0, py1, py2, py3};
        float PZ[4] = {pz0, pz1, pz2, pz3};
#pragma unroll
        for (int k = 0; k < 4; ++k) {
            int flat = (vox_coord(PX[k], mnx) * GG + vox_coord(PY[k], mny)) * GG +
                       vox_coord(PZ[k], mnz);
            if (flags[flat]) {
                float* s = sb + (size_t)flat * 10;
                atomicAdd(s + 0, 1.0f);
                atomicAdd(s + 1, PX[k]);
                atomicAdd(s + 2, PY[k]);
                atomicAdd(s + 3, PZ[k]);
                atomicAdd(s + 4, PX[k] * PX[k]);
                atomicAdd(s + 5, PX[k] * PY[k]);
                atomicAdd(s + 6, PX[k] * PZ[k]);
                atomicAdd(s + 7, PY[k] * PY[k]);
                atomicAdd(s + 8, PY[k] * PZ[k]);
                atomicAdd(s + 9, PZ[k] * PZ[k]);
            }
        }
    }

    grid.sync();   // all sums complete

    // ---- P4: blocks x in {0,1} finalize (flats already in registers) ----
    if (blockIdx.x < 2) {
        int s = blockIdx.x * 256 + threadIdx.x;          // sample id in batch b
        int flat = (blockIdx.x == 0) ? myflat0 : myflat1;
        const float* sm = sums + ((size_t)b * VV + flat) * 10;
        float cnt = sm[0];
        float inv = 1.0f / fmaxf(cnt, 1.0f);
        float ax = sm[1] * inv, ay = sm[2] * inv, az = sm[3] * inv;
        float cxx = sm[4] * inv - ax * ax;
        float cxy = sm[5] * inv - ax * ay;
        float cxz = sm[6] * inv - ax * az;
        float cyy = sm[7] * inv - ay * ay;
        float cyz = sm[8] * inv - ay * az;
        float czz = sm[9] * inv - az * az;
        float* o = out + ((size_t)b * MM + s) * 12;
        o[0] = ax;  o[1] = ay;  o[2] = az;
        o[3] = cxx; o[4] = cxy; o[5] = cxz;
        o[6] = cxy; o[7] = cyy; o[8] = cyz;
        o[9] = cxz; o[10] = cyz; o[11] = czz;
    }
}

extern "C" void kernel_launch(void* const* d_in, const int* in_sizes, int n_in,
                              void* d_out, int out_size, void* d_ws, size_t ws_size,
                              hipStream_t stream) {
    const float* x = (const float*)d_in[0];   // (B, N, 3) fp32
    const int* sidx = (const int*)d_in[1];    // (B, M) int32
    float* out = (float*)d_out;               // (B, M, 12) fp32
    char* ws = (char*)d_ws;

    void* args[] = {(void*)&x, (void*)&sidx, (void*)&ws, (void*)&out};
    hipLaunchCooperativeKernel((void*)vox_coop, dim3(NBLKX, BB), dim3(256),
                               args, 0, stream);
}

// Round 5
// 80.777 us; speedup vs baseline: 1.6371x; 1.6371x over previous
//
#include <hip/hip_runtime.h>

// Problem constants (match reference)
#define BB 2
#define NN 131072
#define MM 512
#define GG 20
#define VV (GG * GG * GG)      // 8000
#define NBLKX 128              // blocks per batch for min/accum

// Workspace layout:
//   0       partialMin : B*NBLKX*3 floats (3072 B)  -- written K1 (no init needed)
//   3072    minVals    : B*3 floats (24 B)          -- written K2
//   3200    sflat      : B*M ints (4096 B)          -- written K2
//   8192    Z-region (zeroed distributed inside K1):
//   8192      flags : B*V bytes (16000 B, pad to 16384)
//   24576     sums  : B*V*10 floats (640000 B)
#define OFF_PARTIAL 0
#define OFF_MINV    3072
#define OFF_SFLAT   3200
#define OFF_FLAGS   8192
#define OFF_SUMS    24576
#define ZWORDS      ((16384 + 640000) / 4)   // 164096 words starting at OFF_FLAGS

__device__ __forceinline__ int vox_coord(float p, float mn) {
    int i = (int)floorf((p - mn) * 2.0f);   // *2 == /0.5 (exact pow2 scale)
    return min(max(i, 0), GG - 1);
}

// ---- K1: distributed zero of Z-region + per-block coordinate-min partials
__global__ __launch_bounds__(256) void vox_min(const float* __restrict__ x,
                                               char* __restrict__ ws) {
    const int b = blockIdx.y;
    const int tid = blockIdx.x * 256 + threadIdx.x;                 // per batch
    const int gtid = (b * NBLKX + blockIdx.x) * 256 + threadIdx.x;  // global

    // zero flags + sums (read only by later kernels; no ordering hazard)
    {
        int* z = (int*)(ws + OFF_FLAGS);
        for (int i = gtid; i < ZWORDS; i += NBLKX * BB * 256) z[i] = 0;
    }

    // one group of 3 float4 (= 4 points) per thread
    const float4* xb = (const float4*)(x + (size_t)b * NN * 3);
    float4 f0 = xb[3 * tid + 0];
    float4 f1 = xb[3 * tid + 1];
    float4 f2 = xb[3 * tid + 2];
    float mx = fminf(fminf(f0.x, f0.w), fminf(f1.z, f2.y));
    float my = fminf(fminf(f0.y, f1.x), fminf(f1.w, f2.z));
    float mz = fminf(fminf(f0.z, f1.y), fminf(f2.x, f2.w));

    for (int off = 32; off > 0; off >>= 1) {
        mx = fminf(mx, __shfl_down(mx, off, 64));
        my = fminf(my, __shfl_down(my, off, 64));
        mz = fminf(mz, __shfl_down(mz, off, 64));
    }
    __shared__ float lmin[4][3];
    int wave = threadIdx.x >> 6;
    if ((threadIdx.x & 63) == 0) {
        lmin[wave][0] = mx; lmin[wave][1] = my; lmin[wave][2] = mz;
    }
    __syncthreads();
    if (threadIdx.x == 0) {
        float* pm = (float*)(ws + OFF_PARTIAL) + (b * NBLKX + blockIdx.x) * 3;
        pm[0] = fminf(fminf(lmin[0][0], lmin[1][0]), fminf(lmin[2][0], lmin[3][0]));
        pm[1] = fminf(fminf(lmin[0][1], lmin[1][1]), fminf(lmin[2][1], lmin[3][1]));
        pm[2] = fminf(fminf(lmin[0][2], lmin[1][2]), fminf(lmin[2][2], lmin[3][2]));
    }
}

// ---- K2: reduce partials + mark sampled voxels (1 block x 1024) --------
__global__ __launch_bounds__(1024) void vox_mark(const float* __restrict__ x,
                                                 const int* __restrict__ sidx,
                                                 char* __restrict__ ws) {
    __shared__ float smin[BB][3];
    const int t = threadIdx.x;

    // 6 (b,axis) pairs x 64 lanes: each lane folds 2 of the 128 partials
    if (t < 384) {
        int pair = t >> 6;            // 0..5
        int lane = t & 63;
        int pb = pair / 3, axis = pair % 3;
        const float* pm = (const float*)(ws + OFF_PARTIAL);
        float m = fminf(pm[(pb * NBLKX + lane) * 3 + axis],
                        pm[(pb * NBLKX + lane + 64) * 3 + axis]);
        for (int off = 32; off > 0; off >>= 1)
            m = fminf(m, __shfl_down(m, off, 64));
        if (lane == 0) {
            smin[pb][axis] = m;
            ((float*)(ws + OFF_MINV))[pb * 3 + axis] = m;
        }
    }
    __syncthreads();

    // mark: t in [0, B*M)
    int b = t >> 9;                   // t / M (M=512)
    int pi = sidx[t];
    const float* p = x + ((size_t)b * NN + pi) * 3;
    int ix = vox_coord(p[0], smin[b][0]);
    int iy = vox_coord(p[1], smin[b][1]);
    int iz = vox_coord(p[2], smin[b][2]);
    int flat = (ix * GG + iy) * GG + iz;
    ((int*)(ws + OFF_SFLAT))[t] = flat;
    ((unsigned char*)(ws + OFF_FLAGS))[b * VV + flat] = 1;
}

// ---- K3: accumulate sums for flagged voxels ----------------------------
// sums per (b,voxel): [cnt, sx, sy, sz, sxx, sxy, sxz, syy, syz, szz]
__global__ __launch_bounds__(256) void vox_accum(const float* __restrict__ x,
                                                 char* __restrict__ ws) {
    const int b = blockIdx.y;
    const int tid = blockIdx.x * 256 + threadIdx.x;
    const float* mv = (const float*)(ws + OFF_MINV) + b * 3;
    const float mnx = mv[0], mny = mv[1], mnz = mv[2];
    const unsigned char* flags = (const unsigned char*)(ws + OFF_FLAGS) + b * VV;
    float* sums = (float*)(ws + OFF_SUMS) + (size_t)b * VV * 10;

    const float4* xb = (const float4*)(x + (size_t)b * NN * 3);
    float4 f0 = xb[3 * tid + 0];
    float4 f1 = xb[3 * tid + 1];
    float4 f2 = xb[3 * tid + 2];
    float px[4] = {f0.x, f0.w, f1.z, f2.y};
    float py[4] = {f0.y, f1.x, f1.w, f2.z};
    float pz[4] = {f0.z, f1.y, f2.x, f2.w};
#pragma unroll
    for (int k = 0; k < 4; ++k) {
        int ix = vox_coord(px[k], mnx);
        int iy = vox_coord(py[k], mny);
        int iz = vox_coord(pz[k], mnz);
        int flat = (ix * GG + iy) * GG + iz;
        if (flags[flat]) {
            float* s = sums + (size_t)flat * 10;
            atomicAdd(s + 0, 1.0f);
            atomicAdd(s + 1, px[k]);
            atomicAdd(s + 2, py[k]);
            atomicAdd(s + 3, pz[k]);
            atomicAdd(s + 4, px[k] * px[k]);
            atomicAdd(s + 5, px[k] * py[k]);
            atomicAdd(s + 6, px[k] * pz[k]);
            atomicAdd(s + 7, py[k] * py[k]);
            atomicAdd(s + 8, py[k] * pz[k]);
            atomicAdd(s + 9, pz[k] * pz[k]);
        }
    }
}

// ---- K4: finalize mean/cov at sampled voxels ---------------------------
__global__ __launch_bounds__(256) void vox_final(const char* __restrict__ ws,
                                                 float* __restrict__ out) {
    int t = blockIdx.x * 256 + threadIdx.x;
    if (t >= BB * MM) return;
    int b = t >> 9;
    int flat = ((const int*)(ws + OFF_SFLAT))[t];
    const float* s = (const float*)(ws + OFF_SUMS) + ((size_t)b * VV + flat) * 10;
    float cnt = s[0];
    float inv = 1.0f / fmaxf(cnt, 1.0f);
    float mx = s[1] * inv, my = s[2] * inv, mz = s[3] * inv;
    float cxx = s[4] * inv - mx * mx;
    float cxy = s[5] * inv - mx * my;
    float cxz = s[6] * inv - mx * mz;
    float cyy = s[7] * inv - my * my;
    float cyz = s[8] * inv - my * mz;
    float czz = s[9] * inv - mz * mz;
    float* o = out + (size_t)t * 12;
    o[0] = mx;  o[1] = my;  o[2] = mz;
    o[3] = cxx; o[4] = cxy; o[5] = cxz;
    o[6] = cxy; o[7] = cyy; o[8] = cyz;
    o[9] = cxz; o[10] = cyz; o[11] = czz;
}

extern "C" void kernel_launch(void* const* d_in, const int* in_sizes, int n_in,
                              void* d_out, int out_size, void* d_ws, size_t ws_size,
                              hipStream_t stream) {
    const float* x = (const float*)d_in[0];   // (B, N, 3) fp32
    const int* sidx = (const int*)d_in[1];    // (B, M) int32
    float* out = (float*)d_out;               // (B, M, 12) fp32
    char* ws = (char*)d_ws;

    vox_min<<<dim3(NBLKX, BB), 256, 0, stream>>>(x, ws);
    vox_mark<<<1, 1024, 0, stream>>>(x, sidx, ws);
    vox_accum<<<dim3(NBLKX, BB), 256, 0, stream>>>(x, ws);
    vox_final<<<(BB * MM + 255) / 256, 256, 0, stream>>>(ws, out);
}